// Round 2
// 618.744 us; speedup vs baseline: 1.0401x; 1.0401x over previous
//
#include <hip/hip_runtime.h>
#include <hip/hip_bf16.h>

#define E_ 8
#define D_ 1024
#define H_ 4096
#define N_ 8192

typedef __attribute__((ext_vector_type(8))) short bf16x8;   // MFMA A/B frag: 8 bf16 = 4 VGPRs
typedef __attribute__((ext_vector_type(4))) float f32x4;    // MFMA C/D frag
typedef __attribute__((ext_vector_type(4))) float fv4;      // native float4 (for NT builtins)
typedef unsigned short u16;

// fp32 -> bf16 round-to-nearest-even
static __device__ __forceinline__ u16 f2bf(float f) {
    unsigned int u = __float_as_uint(f);
    u += 0x7fffu + ((u >> 16) & 1u);
    return (u16)(u >> 16);
}

static __device__ __forceinline__ void st_bf4(u16* p, float4 v) {
    union { u16 u[4]; unsigned long long ll; } t;
    t.u[0] = f2bf(v.x); t.u[1] = f2bf(v.y); t.u[2] = f2bf(v.z); t.u[3] = f2bf(v.w);
    *(unsigned long long*)p = t.ll;
}

static __device__ __forceinline__ float gelu_tanh(float x) {
    float x3 = x * x * x;
    float z = 0.7978845608028654f * (x + 0.044715f * x3);
    float t = 1.0f - 2.0f / (1.0f + __expf(2.0f * z));  // tanh(z)
    return 0.5f * x * (1.0f + t);
}

static __device__ __forceinline__ int expert_of(const int* __restrict__ ntpe, int row) {
    int acc = 0;
    #pragma unroll
    for (int i = 0; i < E_; ++i) {
        acc += ntpe[i];
        if (row < acc) return i;
    }
    return E_ - 1;
}

// async 16B/lane global -> LDS. lds base must be wave-uniform; data lands at base + lane*16.
#define GLD16(gp, lp) __builtin_amdgcn_global_load_lds( \
    (const __attribute__((address_space(1))) void*)(gp), \
    (__attribute__((address_space(3))) void*)(lp), 16, 0, 0)

// ---------------------------------------------------------------------------
// Prepass: cast x, w1, w2, w3 fp32 -> bf16. Segmented grid; float8/thread.
// NT loads: fp32 sources are dead after this kernel -- don't allocate them in
// L2/L3, so the freshly written bf16 operands stay cache-resident for gemm13.
// Segment order: w2 first (NT store -- gemm13 thrashes L3 before gemm2 reads
// it anyway), then w1, w3, x last => gemm13's inputs are the hottest lines.
// ---------------------------------------------------------------------------
#define CVT_XBLK 512
#define CVT_WBLK 2048
#define CVT_NBLK (CVT_XBLK + 3 * CVT_WBLK)

__global__ __launch_bounds__(256) void cvt_all2(
    const float* __restrict__ x, const float* __restrict__ w1,
    const float* __restrict__ w2, const float* __restrict__ w3,
    u16* __restrict__ xb, u16* __restrict__ w1b,
    u16* __restrict__ w2b, u16* __restrict__ w3b)
{
    int b = blockIdx.x;
    const float* src; u16* dst; int n8; int b0; int nb; bool nts = false;
    if (b < CVT_WBLK) {
        src = w2; dst = w2b; n8 = E_ * D_ * H_ / 8; b0 = 0; nb = CVT_WBLK; nts = true;
    } else if (b < 2 * CVT_WBLK) {
        src = w1; dst = w1b; n8 = E_ * H_ * D_ / 8; b0 = CVT_WBLK; nb = CVT_WBLK;
    } else if (b < 3 * CVT_WBLK) {
        src = w3; dst = w3b; n8 = E_ * H_ * D_ / 8; b0 = 2 * CVT_WBLK; nb = CVT_WBLK;
    } else {
        src = x; dst = xb; n8 = N_ * D_ / 8; b0 = 3 * CVT_WBLK; nb = CVT_XBLK;
    }
    int t = (b - b0) * 256 + threadIdx.x;
    int stride = nb * 256;
    const fv4* s4 = (const fv4*)src;
    for (int i = t; i < n8; i += stride) {
        fv4 a = __builtin_nontemporal_load(s4 + (size_t)i * 2);
        fv4 c = __builtin_nontemporal_load(s4 + (size_t)i * 2 + 1);
        union { u16 u[8]; bf16x8 v; } o;
        o.u[0] = f2bf(a.x); o.u[1] = f2bf(a.y); o.u[2] = f2bf(a.z); o.u[3] = f2bf(a.w);
        o.u[4] = f2bf(c.x); o.u[5] = f2bf(c.y); o.u[6] = f2bf(c.z); o.u[7] = f2bf(c.w);
        if (nts) __builtin_nontemporal_store(o.v, (bf16x8*)(dst + (size_t)i * 8));
        else *(bf16x8*)(dst + (size_t)i * 8) = o.v;
    }
}

// ---------------------------------------------------------------------------
// LDS swizzle: row r (128 B = 8x16B chunks) stores global chunk c at slot
// c ^ (r & 7). Frag read for lane(fr,quad), k-half kh: slot (quad+4kh)^(fr&7)
// -> 16B-slot group covers all 8 groups twice per quad-group => conflict-free.
// Staging: lane L -> row_rel L>>3, slot L&7, source chunk (L&7)^((L>>3)&7).
// ---------------------------------------------------------------------------

// Kernel 1: h = gelu_tanh(x@w1^T) * (x@w3^T). BM=128, BN=64, BK=64.
// 4 waves 2x2 (wave tile 64x32). Dual acc 4x2 = 64 AGPRs. 32 KB LDS, 3 blk/CU.
// Grid: 1D 4096, XCD-chunk swizzled + expert-major / n-group / m-minor order:
// the 8 m-blocks sharing one (e,n) weight tile are dispatch-adjacent on one
// XCD (weight reuse L3->L2); each XCD owns exactly one expert (~18 MiB unique).
#define EPIT 72   // epilogue LDS pitch (u16)

__global__ __launch_bounds__(256, 3) void moe_gemm13_fast(
    const u16* __restrict__ xb, const u16* __restrict__ w1b,
    const u16* __restrict__ w3b, const int* __restrict__ ntpe,
    u16* __restrict__ hbuf)
{
    __shared__ u16 smem[16384];      // 32 KB staging; epilogue reuses 9216 el
    u16* sA  = smem;                 // 128x64
    u16* sB1 = smem + 8192;          // 64x64
    u16* sB2 = smem + 12288;         // 64x64

    const int tid = threadIdx.x;
    // XCD-chunk swizzle (4096 % 8 == 0 -> bijective), then decode
    // L = eg*512 + ng*8 + mi  (eg: expert-group of 8 m-blocks, ng: n-block).
    const int bswz = (blockIdx.x & 7) * (4096 / 8) + (blockIdx.x >> 3);
    const int eg = bswz >> 9;
    const int rr = bswz & 511;
    const int m0 = (eg * 8 + (rr & 7)) * 128;
    const int n0 = (rr >> 3) * 64;
    const int e = expert_of(ntpe, m0);
    const int wave = tid >> 6, lane = tid & 63;
    const int wm = (wave >> 1) * 64, wn = (wave & 1) * 32;
    const int fr = lane & 15, quad = lane >> 4;
    const int sw = fr & 7;

    const u16* Ag  = xb  + (size_t)m0 * D_;
    const u16* B1g = w1b + ((size_t)e * H_ + n0) * D_;
    const u16* B2g = w3b + ((size_t)e * H_ + n0) * D_;

    const int srr = lane >> 3;                 // row within 8-row group
    const int scg = ((lane & 7) ^ srr) * 8;    // swizzled source col (elements)

    f32x4 accg[4][2], accu[4][2];
    #pragma unroll
    for (int i = 0; i < 4; ++i)
        #pragma unroll
        for (int j = 0; j < 2; ++j) {
            accg[i][j] = (f32x4){0.f, 0.f, 0.f, 0.f};
            accu[i][j] = (f32x4){0.f, 0.f, 0.f, 0.f};
        }

    for (int k0 = 0; k0 < D_; k0 += 64) {
        #pragma unroll
        for (int c = 0; c < 4; ++c)
            GLD16(Ag + (size_t)(wave * 32 + c * 8 + srr) * D_ + k0 + scg,
                  sA + (wave * 32 + c * 8) * 64);
        #pragma unroll
        for (int c = 0; c < 2; ++c) {
            GLD16(B1g + (size_t)(wave * 16 + c * 8 + srr) * D_ + k0 + scg,
                  sB1 + (wave * 16 + c * 8) * 64);
            GLD16(B2g + (size_t)(wave * 16 + c * 8 + srr) * D_ + k0 + scg,
                  sB2 + (wave * 16 + c * 8) * 64);
        }
        __syncthreads();

        #pragma unroll
        for (int kh = 0; kh < 2; ++kh) {
            const int ks = ((quad + kh * 4) ^ sw) * 8;
            bf16x8 fa[4], fb1[2], fb2[2];
            #pragma unroll
            for (int i = 0; i < 4; ++i)
                fa[i] = *(const bf16x8*)(&sA[(wm + i * 16 + fr) * 64 + ks]);
            #pragma unroll
            for (int j = 0; j < 2; ++j) {
                fb1[j] = *(const bf16x8*)(&sB1[(wn + j * 16 + fr) * 64 + ks]);
                fb2[j] = *(const bf16x8*)(&sB2[(wn + j * 16 + fr) * 64 + ks]);
            }
            #pragma unroll
            for (int i = 0; i < 4; ++i)
                #pragma unroll
                for (int j = 0; j < 2; ++j) {
                    accg[i][j] = __builtin_amdgcn_mfma_f32_16x16x32_bf16(fa[i], fb1[j], accg[i][j], 0, 0, 0);
                    accu[i][j] = __builtin_amdgcn_mfma_f32_16x16x32_bf16(fa[i], fb2[j], accu[i][j], 0, 0, 0);
                }
        }
        __syncthreads();
    }

    // Epilogue: gelu(g)*u -> LDS tile (pitch EPIT) -> coalesced 16B stores
    #pragma unroll
    for (int i = 0; i < 4; ++i) {
        int rl = wm + i * 16 + quad * 4;
        #pragma unroll
        for (int j = 0; j < 2; ++j) {
            int cl = wn + j * 16 + fr;
            #pragma unroll
            for (int r = 0; r < 4; ++r) {
                float hv = gelu_tanh(accg[i][j][r]) * accu[i][j][r];
                smem[(rl + r) * EPIT + cl] = f2bf(hv);
            }
        }
    }
    __syncthreads();
    #pragma unroll
    for (int it = 0; it < 4; ++it) {
        int chunk = it * 256 + tid;          // [0,1024)
        int row = chunk >> 3;
        int col = (chunk & 7) * 8;
        bf16x8 v = *(const bf16x8*)(&smem[row * EPIT + col]);
        *(bf16x8*)(&hbuf[(size_t)(m0 + row) * H_ + n0 + col]) = v;
    }
}

// Kernel 2: out = h @ w2^T (K=4096). BM=128, BN=128, BK=64, swizzled, 32 KB LDS.
// Grid: 1D 512, XCD-chunk swizzled, expert-major / n / m-minor (8 adjacent
// blocks share the 1 MiB w2 tile -> L2 hits; one expert per XCD).
__global__ __launch_bounds__(256, 3) void moe_gemm2_fast(
    const u16* __restrict__ hbuf, const u16* __restrict__ w2b,
    const int* __restrict__ ntpe, float* __restrict__ out)
{
    __shared__ u16 smem[16384];
    u16* sA = smem;                  // 128x64
    u16* sB = smem + 8192;           // 128x64

    const int tid = threadIdx.x;
    const int bswz = (blockIdx.x & 7) * (512 / 8) + (blockIdx.x >> 3);
    const int eg = bswz >> 6;
    const int rr = bswz & 63;
    const int m0 = (eg * 8 + (rr & 7)) * 128;
    const int n0 = (rr >> 3) * 128;
    const int e = expert_of(ntpe, m0);
    const int wave = tid >> 6, lane = tid & 63;
    const int wm = (wave >> 1) * 64, wn = (wave & 1) * 64;
    const int fr = lane & 15, quad = lane >> 4;
    const int sw = fr & 7;

    const u16* Ag = hbuf + (size_t)m0 * H_;
    const u16* Bg = w2b + ((size_t)e * D_ + n0) * H_;

    const int srr = lane >> 3;
    const int scg = ((lane & 7) ^ srr) * 8;

    f32x4 acc[4][4];
    #pragma unroll
    for (int i = 0; i < 4; ++i)
        #pragma unroll
        for (int j = 0; j < 4; ++j)
            acc[i][j] = (f32x4){0.f, 0.f, 0.f, 0.f};

    for (int k0 = 0; k0 < H_; k0 += 64) {
        #pragma unroll
        for (int c = 0; c < 4; ++c) {
            GLD16(Ag + (size_t)(wave * 32 + c * 8 + srr) * H_ + k0 + scg,
                  sA + (wave * 32 + c * 8) * 64);
            GLD16(Bg + (size_t)(wave * 32 + c * 8 + srr) * H_ + k0 + scg,
                  sB + (wave * 32 + c * 8) * 64);
        }
        __syncthreads();

        #pragma unroll
        for (int kh = 0; kh < 2; ++kh) {
            const int ks = ((quad + kh * 4) ^ sw) * 8;
            bf16x8 fa[4], fb[4];
            #pragma unroll
            for (int i = 0; i < 4; ++i) {
                fa[i] = *(const bf16x8*)(&sA[(wm + i * 16 + fr) * 64 + ks]);
                fb[i] = *(const bf16x8*)(&sB[(wn + i * 16 + fr) * 64 + ks]);
            }
            #pragma unroll
            for (int i = 0; i < 4; ++i)
                #pragma unroll
                for (int j = 0; j < 4; ++j)
                    acc[i][j] = __builtin_amdgcn_mfma_f32_16x16x32_bf16(fa[i], fb[j], acc[i][j], 0, 0, 0);
        }
        __syncthreads();
    }

    #pragma unroll
    for (int i = 0; i < 4; ++i) {
        int rowb = m0 + wm + i * 16 + quad * 4;
        #pragma unroll
        for (int j = 0; j < 4; ++j) {
            int col = n0 + wn + j * 16 + fr;
            #pragma unroll
            for (int r = 0; r < 4; ++r)
                __builtin_nontemporal_store(acc[i][j][r], &out[(size_t)(rowb + r) * D_ + col]);
        }
    }
}

// ---------------------------------------------------------------------------
// Fallback (round-1) kernels, used if ws too small
// ---------------------------------------------------------------------------
#define LDSP 40

__global__ __launch_bounds__(256, 2) void moe_gemm13_slow(
    const float* __restrict__ x, const float* __restrict__ w1,
    const float* __restrict__ w3, const int* __restrict__ ntpe,
    u16* __restrict__ hbuf)
{
    const int tid = threadIdx.x;
    const int m0 = blockIdx.y * 128, n0 = blockIdx.x * 128;
    const int e = expert_of(ntpe, m0);
    __shared__ u16 sA[128][LDSP]; __shared__ u16 sB1[128][LDSP]; __shared__ u16 sB2[128][LDSP];
    const int wave = tid >> 6, lane = tid & 63;
    const int wm = (wave >> 1) * 64, wn = (wave & 1) * 64;
    const int fr = lane & 15, quad = lane >> 4;
    f32x4 accg[4][4], accu[4][4];
    #pragma unroll
    for (int i = 0; i < 4; ++i)
        #pragma unroll
        for (int j = 0; j < 4; ++j) {
            accg[i][j] = (f32x4){0.f,0.f,0.f,0.f}; accu[i][j] = (f32x4){0.f,0.f,0.f,0.f};
        }
    const float* Ab  = x  + (size_t)m0 * D_;
    const float* B1b = w1 + ((size_t)e * H_ + n0) * D_;
    const float* B2b = w3 + ((size_t)e * H_ + n0) * D_;
    for (int k0 = 0; k0 < D_; k0 += 32) {
        #pragma unroll
        for (int s = 0; s < 4; ++s) {
            int idx = s * 256 + tid;
            int row = idx >> 3, col = (idx & 7) * 4;
            size_t go = (size_t)row * D_ + k0 + col;
            st_bf4(&sA[row][col],  *(const float4*)(Ab + go));
            st_bf4(&sB1[row][col], *(const float4*)(B1b + go));
            st_bf4(&sB2[row][col], *(const float4*)(B2b + go));
        }
        __syncthreads();
        bf16x8 fa[4], fb1[4], fb2[4];
        #pragma unroll
        for (int i = 0; i < 4; ++i) {
            fa[i]  = *(const bf16x8*)(&sA[wm + i * 16 + fr][quad * 8]);
            fb1[i] = *(const bf16x8*)(&sB1[wn + i * 16 + fr][quad * 8]);
            fb2[i] = *(const bf16x8*)(&sB2[wn + i * 16 + fr][quad * 8]);
        }
        #pragma unroll
        for (int i = 0; i < 4; ++i)
            #pragma unroll
            for (int j = 0; j < 4; ++j) {
                accg[i][j] = __builtin_amdgcn_mfma_f32_16x16x32_bf16(fa[i], fb1[j], accg[i][j], 0, 0, 0);
                accu[i][j] = __builtin_amdgcn_mfma_f32_16x16x32_bf16(fa[i], fb2[j], accu[i][j], 0, 0, 0);
            }
        __syncthreads();
    }
    #pragma unroll
    for (int i = 0; i < 4; ++i) {
        int rowb = m0 + wm + i * 16 + quad * 4;
        #pragma unroll
        for (int j = 0; j < 4; ++j) {
            int col = n0 + wn + j * 16 + fr;
            #pragma unroll
            for (int r = 0; r < 4; ++r)
                hbuf[(size_t)(rowb + r) * H_ + col] = f2bf(gelu_tanh(accg[i][j][r]) * accu[i][j][r]);
        }
    }
}

__global__ __launch_bounds__(256, 2) void moe_gemm2_slow(
    const u16* __restrict__ hbuf, const float* __restrict__ w2,
    const int* __restrict__ ntpe, float* __restrict__ out)
{
    const int tid = threadIdx.x;
    const int m0 = blockIdx.y * 128, n0 = blockIdx.x * 128;
    const int e = expert_of(ntpe, m0);
    __shared__ u16 sA[128][LDSP]; __shared__ u16 sB[128][LDSP];
    const int wave = tid >> 6, lane = tid & 63;
    const int wm = (wave >> 1) * 64, wn = (wave & 1) * 64;
    const int fr = lane & 15, quad = lane >> 4;
    f32x4 acc[4][4];
    #pragma unroll
    for (int i = 0; i < 4; ++i)
        #pragma unroll
        for (int j = 0; j < 4; ++j) acc[i][j] = (f32x4){0.f,0.f,0.f,0.f};
    const u16* Ab = hbuf + (size_t)m0 * H_;
    const float* Bb = w2 + ((size_t)e * D_ + n0) * H_;
    for (int k0 = 0; k0 < H_; k0 += 32) {
        #pragma unroll
        for (int s = 0; s < 2; ++s) {
            int idx = s * 256 + tid;
            int row = idx >> 2, col = (idx & 3) * 8;
            *(bf16x8*)(&sA[row][col]) = *(const bf16x8*)(Ab + (size_t)row * H_ + k0 + col);
        }
        #pragma unroll
        for (int s = 0; s < 4; ++s) {
            int idx = s * 256 + tid;
            int row = idx >> 3, col = (idx & 7) * 4;
            st_bf4(&sB[row][col], *(const float4*)(Bb + (size_t)row * H_ + k0 + col));
        }
        __syncthreads();
        bf16x8 fa[4], fb[4];
        #pragma unroll
        for (int i = 0; i < 4; ++i) {
            fa[i] = *(const bf16x8*)(&sA[wm + i * 16 + fr][quad * 8]);
            fb[i] = *(const bf16x8*)(&sB[wn + i * 16 + fr][quad * 8]);
        }
        #pragma unroll
        for (int i = 0; i < 4; ++i)
            #pragma unroll
            for (int j = 0; j < 4; ++j)
                acc[i][j] = __builtin_amdgcn_mfma_f32_16x16x32_bf16(fa[i], fb[j], acc[i][j], 0, 0, 0);
        __syncthreads();
    }
    #pragma unroll
    for (int i = 0; i < 4; ++i) {
        int rowb = m0 + wm + i * 16 + quad * 4;
        #pragma unroll
        for (int j = 0; j < 4; ++j) {
            int col = n0 + wn + j * 16 + fr;
            #pragma unroll
            for (int r = 0; r < 4; ++r)
                out[(size_t)(rowb + r) * D_ + col] = acc[i][j][r];
        }
    }
}

extern "C" void kernel_launch(void* const* d_in, const int* in_sizes, int n_in,
                              void* d_out, int out_size, void* d_ws, size_t ws_size,
                              hipStream_t stream) {
    const float* x  = (const float*)d_in[0];
    const float* w1 = (const float*)d_in[1];
    const float* w2 = (const float*)d_in[2];
    const float* w3 = (const float*)d_in[3];
    const int* ntpe = (const int*)d_in[4];
    float* out = (float*)d_out;

    // ws layout (bytes): xb 16M | w1b 64M | w3b 64M | w2b 64M | h 64M = 272 MB
    const size_t SZ_XB = (size_t)N_ * D_ * 2;
    const size_t SZ_W  = (size_t)E_ * H_ * D_ * 2;
    const size_t SZ_H  = (size_t)N_ * H_ * 2;
    const size_t NEED  = SZ_XB + 3 * SZ_W + SZ_H;

    if (ws_size >= NEED) {
        char* p = (char*)d_ws;
        u16* xb  = (u16*)p;                 p += SZ_XB;
        u16* w1b = (u16*)p;                 p += SZ_W;
        u16* w3b = (u16*)p;                 p += SZ_W;
        u16* w2b = (u16*)p;                 p += SZ_W;
        u16* hb  = (u16*)p;

        cvt_all2<<<CVT_NBLK, 256, 0, stream>>>(x, w1, w2, w3, xb, w1b, w2b, w3b);

        moe_gemm13_fast<<<4096, 256, 0, stream>>>(xb, w1b, w3b, ntpe, hb);

        moe_gemm2_fast<<<512, 256, 0, stream>>>(hb, w2b, ntpe, out);
    } else {
        u16* hb = (u16*)d_ws;  // 64 MB
        dim3 g1(H_ / 128, N_ / 128);
        moe_gemm13_slow<<<g1, 256, 0, stream>>>(x, w1, w3, ntpe, hb);
        dim3 g2(D_ / 128, N_ / 128);
        moe_gemm2_slow<<<g2, 256, 0, stream>>>(hb, w2, ntpe, out);
    }
}